// Round 1
// baseline (491.139 us; speedup 1.0000x reference)
//
#include <hip/hip_runtime.h>

typedef _Float16 f16x8 __attribute__((ext_vector_type(8)));
typedef _Float16 f16x4 __attribute__((ext_vector_type(4)));
typedef float    f32x4 __attribute__((ext_vector_type(4)));

#define MFMA16(a,b,c) __builtin_amdgcn_mfma_f32_16x16x32_f16((a),(b),(c),0,0,0)

constexpr int Bc  = 8;
constexpr int Sc  = 1024;
constexpr int Hc  = 512;
constexpr int NHc = 8;
constexpr int HDc = 64;

// ---------------------------------------------------------------------------
// Stage 0: fp32 -> fp16 convert of hs and the three W matrices (concatenated).
// ---------------------------------------------------------------------------
__global__ __launch_bounds__(256) void cvt_f16(
    const float* __restrict__ hs,
    const float* __restrict__ wq, const float* __restrict__ wk,
    const float* __restrict__ wv,
    _Float16* __restrict__ hs16, _Float16* __restrict__ w16)
{
    const size_t i4  = (size_t)blockIdx.x * 256 + threadIdx.x;  // float4 index
    const size_t HS4 = (size_t)Bc * Sc * Hc / 4;   // 1,048,576
    const size_t W4  = (size_t)Hc * Hc / 4;        // 65,536
    float4 v;
    _Float16* dst;
    if (i4 < HS4) {
        v = ((const float4*)hs)[i4];
        dst = hs16 + i4 * 4;
    } else {
        const size_t j = i4 - HS4;
        const int z = (int)(j / W4);
        const size_t o = j - (size_t)z * W4;
        const float* src = (z == 0) ? wq : (z == 1) ? wk : wv;
        v = ((const float4*)src)[o];
        dst = w16 + j * 4;
    }
    f16x4 h;
    h[0] = (_Float16)v.x; h[1] = (_Float16)v.y;
    h[2] = (_Float16)v.z; h[3] = (_Float16)v.w;
    *(f16x4*)dst = h;
}

// ---------------------------------------------------------------------------
// Stage 1: fused QKV GEMM, m97-style (unchanged).
// ---------------------------------------------------------------------------
__global__ __launch_bounds__(256) void qkv_gemm(
    const _Float16* __restrict__ A,   // [8192][512]
    const _Float16* __restrict__ Bm,  // [1536][512]
    const float* __restrict__ bq, const float* __restrict__ bk,
    const float* __restrict__ bv,
    _Float16* __restrict__ qws, _Float16* __restrict__ kws,
    _Float16* __restrict__ vws)
{
    __shared__ __align__(16) _Float16 As[128 * 64];
    __shared__ __align__(16) _Float16 Bs[128 * 64];

    const int m0 = blockIdx.x * 128;
    const int n0 = blockIdx.y * 128;
    const int tid  = threadIdx.x;
    const int lane = tid & 63;
    const int w    = tid >> 6;
    const int l15  = lane & 15;
    const int quad = lane >> 4;
    const int wm   = (w >> 1) * 64;
    const int wn   = (w & 1) * 64;

    f32x4 acc[4][4] = {};

    const int srow = tid >> 3;
    const int scol = (tid & 7) * 8;

    for (int k0 = 0; k0 < 512; k0 += 64) {
        __syncthreads();
#pragma unroll
        for (int j = 0; j < 4; ++j) {
            const _Float16* ga = A  + (size_t)(m0 + srow + 32 * j) * 512 + k0 + scol;
            const _Float16* gb = Bm + (size_t)(n0 + srow + 32 * j) * 512 + k0 + scol;
            __builtin_amdgcn_global_load_lds(
                (const __attribute__((address_space(1))) void*)ga,
                (__attribute__((address_space(3))) void*)(As + tid * 8 + j * 2048),
                16, 0, 0);
            __builtin_amdgcn_global_load_lds(
                (const __attribute__((address_space(1))) void*)gb,
                (__attribute__((address_space(3))) void*)(Bs + tid * 8 + j * 2048),
                16, 0, 0);
        }
        __syncthreads();
#pragma unroll
        for (int ks = 0; ks < 2; ++ks) {
            f16x8 af[4], bf[4];
#pragma unroll
            for (int i = 0; i < 4; ++i) {
                af[i] = *(const f16x8*)&As[(wm + i * 16 + l15) * 64 + ks * 32 + quad * 8];
                bf[i] = *(const f16x8*)&Bs[(wn + i * 16 + l15) * 64 + ks * 32 + quad * 8];
            }
#pragma unroll
            for (int mb = 0; mb < 4; ++mb)
#pragma unroll
                for (int nb = 0; nb < 4; ++nb)
                    acc[mb][nb] = MFMA16(af[mb], bf[nb], acc[mb][nb]);
        }
    }

    const int zsel = n0 >> 9;
    const float* bias = (zsel == 0) ? bq : (zsel == 1) ? bk : bv;
#pragma unroll
    for (int nb = 0; nb < 4; ++nb) {
        const int n  = n0 + wn + nb * 16 + l15;
        const int nn = n & 511;
        const int h  = nn >> 6;
        const int hd = nn & 63;
        const float bvv = bias[nn];
#pragma unroll
        for (int mb = 0; mb < 4; ++mb) {
            const int m = m0 + wm + mb * 16 + quad * 4;
            const int b = m >> 10;
            const int s = m & 1023;
            if (zsel == 2) {
                f16x4 t;
#pragma unroll
                for (int rr = 0; rr < 4; ++rr)
                    t[rr] = (_Float16)(acc[mb][nb][rr] + bvv);
                *(f16x4*)&vws[((size_t)(b * NHc + h) * HDc + hd) * Sc + s] = t;
            } else {
                _Float16* dst = (zsel == 0 ? qws : kws)
                              + ((size_t)(b * NHc + h) * Sc + s) * HDc + hd;
#pragma unroll
                for (int rr = 0; rr < 4; ++rr)
                    dst[(size_t)rr * HDc] = (_Float16)(acc[mb][nb][rr] + bvv);
            }
        }
    }
}

// ---------------------------------------------------------------------------
// Stage 2: flash attention. v5: cross-tile software pipeline.
//
// v4 post-mortem: VGPR_Count=56 proved the compiler serialized the "hoisted"
// loads (≈2 outstanding/wave -> 1.3 TB/s, MfmaUtil 4%). vmcnt is in-order, so
// any in-tile hoist dies at the first MFMA's wait. v5 double-buffers the rel
// tile in REGISTERS across k-tiles with a vmcnt-compatible issue order:
//   mask -> K -> V -> QK -> softmax(rel cur) -> [SB] rel(kt+1) [SB] -> Plds -> PV
// * QK's wait on K (vmcnt<=8) drains rel(kt) exactly when softmax needs it.
// * PV's wait on V is vmcnt(16): rel(kt+1) SURVIVES PV and stays in flight
//   across Plds+PV+next K+QK ~= 900 cy = one full HBM latency.
// * V is issued up front so its ~200 cy L2 latency hides under QK+softmax.
// sched_barrier(0) fences pin the rel prefetch so the scheduler cannot hoist
// it above the K/V issue (which would re-create the in-order drain).
// ~150 VGPR -> __launch_bounds__(128,3): 12 waves/CU, each with ~16-24 loads
// in flight (~48 KB/CU >> the ~9 KB needed to saturate HBM).
// ---------------------------------------------------------------------------
__global__ __launch_bounds__(128, 3) void attn(
    const _Float16* __restrict__ qws, const _Float16* __restrict__ kws,
    const _Float16* __restrict__ vws, const float* __restrict__ rel,
    const float* __restrict__ mask, float* __restrict__ out)
{
    const int qt = blockIdx.x;      // 0..31 (32 q-rows per block)
    const int bh = blockIdx.y;      // 0..63
    const int b  = bh >> 3;
    const int h  = bh & 7;
    const int tid  = threadIdx.x;
    const int w    = tid >> 6;      // 0..1
    const int lane = tid & 63;
    const int l15  = lane & 15;
    const int quad = lane >> 4;
    const int q0w  = qt * 32 + w * 16;

    __shared__ __align__(16) _Float16 lds_p[2][16][72];  // per-wave slice

    const _Float16* qh = qws + (size_t)bh * Sc * HDc;
    const _Float16* kh = kws + (size_t)bh * Sc * HDc;
    const _Float16* vh = vws + (size_t)bh * HDc * Sc;
    const float* relh  = rel + (size_t)bh * Sc * Sc;
    const float* maskb = mask + (size_t)b * Sc;

    f16x8 qf0 = *(const f16x8*)(qh + (size_t)(q0w + l15) * HDc + quad * 8);
    f16x8 qf1 = *(const f16x8*)(qh + (size_t)(q0w + l15) * HDc + 32 + quad * 8);

    float m_run[4], l_run[4];
    f32x4 o[4] = {};
#pragma unroll
    for (int rj = 0; rj < 4; ++rj) { m_run[rj] = -1e30f; l_run[rj] = 0.f; }

    // lane's base into its rel rows: row = q0w + quad*4 (+rj), col base l15
    const float* relp = relh + (size_t)(q0w + quad * 4) * Sc + l15;

    float rbA[16], rbB[16];
    // prologue: prefetch rel tile 0 into rbA
#pragma unroll
    for (int nb = 0; nb < 4; ++nb)
#pragma unroll
        for (int rj = 0; rj < 4; ++rj)
            rbA[nb * 4 + rj] = relp[(size_t)rj * Sc + nb * 16];

#define TILE_BODY(KT, CUR, NXT)                                               \
    {                                                                         \
        const int kbase = (KT) * 64;                                          \
        /* issue order matters for in-order vmcnt: mask, K, V */              \
        float mk[4];                                                          \
        _Pragma("unroll")                                                     \
        for (int nb = 0; nb < 4; ++nb)                                        \
            mk[nb] = maskb[kbase + nb * 16 + l15];                            \
        f16x8 kf0[4], kf1[4];                                                 \
        _Pragma("unroll")                                                     \
        for (int nb = 0; nb < 4; ++nb) {                                      \
            const _Float16* kp = kh + (size_t)(kbase + nb * 16 + l15) * HDc   \
                               + quad * 8;                                    \
            kf0[nb] = *(const f16x8*)kp;                                      \
            kf1[nb] = *(const f16x8*)(kp + 32);                               \
        }                                                                     \
        f16x8 vf0[4], vf1[4];                                                 \
        _Pragma("unroll")                                                     \
        for (int nb = 0; nb < 4; ++nb) {                                      \
            const _Float16* vp = vh + (size_t)(nb * 16 + l15) * Sc + kbase    \
                               + quad * 8;                                    \
            vf0[nb] = *(const f16x8*)vp;                                      \
            vf1[nb] = *(const f16x8*)(vp + 32);                               \
        }                                                                     \
        /* S = Q K^T */                                                       \
        f32x4 sc[4] = {};                                                     \
        _Pragma("unroll")                                                     \
        for (int nb = 0; nb < 4; ++nb) {                                      \
            sc[nb] = MFMA16(qf0, kf0[nb], sc[nb]);                            \
            sc[nb] = MFMA16(qf1, kf1[nb], sc[nb]);                            \
        }                                                                     \
        /* scale + rel bias (loaded LAST tile, drained by the K wait) + mask*/\
        _Pragma("unroll")                                                     \
        for (int nb = 0; nb < 4; ++nb)                                        \
            _Pragma("unroll")                                                 \
            for (int rj = 0; rj < 4; ++rj)                                    \
                sc[nb][rj] = sc[nb][rj] * 0.125f + CUR[nb * 4 + rj] + mk[nb]; \
        /* online softmax (row lives on 16 lanes of one quad) */              \
        _Pragma("unroll")                                                     \
        for (int rj = 0; rj < 4; ++rj) {                                      \
            float mx = fmaxf(fmaxf(sc[0][rj], sc[1][rj]),                     \
                             fmaxf(sc[2][rj], sc[3][rj]));                    \
            _Pragma("unroll")                                                 \
            for (int off = 1; off < 16; off <<= 1)                            \
                mx = fmaxf(mx, __shfl_xor(mx, off));                          \
            const float mnew  = fmaxf(m_run[rj], mx);                         \
            const float alpha = __expf(m_run[rj] - mnew);                     \
            float rs = 0.f;                                                   \
            _Pragma("unroll")                                                 \
            for (int nb = 0; nb < 4; ++nb) {                                  \
                const float p = __expf(sc[nb][rj] - mnew);                    \
                sc[nb][rj] = p;                                               \
                rs += p;                                                      \
            }                                                                 \
            _Pragma("unroll")                                                 \
            for (int off = 1; off < 16; off <<= 1) rs += __shfl_xor(rs, off); \
            m_run[rj] = mnew;                                                 \
            l_run[rj] = l_run[rj] * alpha + rs;                               \
            o[0][rj] *= alpha; o[1][rj] *= alpha;                             \
            o[2][rj] *= alpha; o[3][rj] *= alpha;                             \
        }                                                                     \
        /* prefetch NEXT tile's rel: pinned after V-issue, before Plds/PV */  \
        __builtin_amdgcn_sched_barrier(0);                                    \
        if ((KT) < 15) {                                                      \
            _Pragma("unroll")                                                 \
            for (int nb = 0; nb < 4; ++nb)                                    \
                _Pragma("unroll")                                             \
                for (int rj = 0; rj < 4; ++rj)                                \
                    NXT[nb * 4 + rj] =                                        \
                        relp[(size_t)rj * Sc + kbase + 64 + nb * 16];         \
        }                                                                     \
        __builtin_amdgcn_sched_barrier(0);                                    \
        /* P: C layout -> A layout via per-wave LDS (no barriers) */          \
        _Pragma("unroll")                                                     \
        for (int nb = 0; nb < 4; ++nb)                                        \
            _Pragma("unroll")                                                 \
            for (int rj = 0; rj < 4; ++rj)                                    \
                lds_p[w][quad * 4 + rj][nb * 16 + l15] =                      \
                    (_Float16)sc[nb][rj];                                     \
        f16x8 ap0 = *(const f16x8*)&lds_p[w][l15][quad * 8];                  \
        f16x8 ap1 = *(const f16x8*)&lds_p[w][l15][32 + quad * 8];             \
        /* O += P V  (V preloaded at tile top; wait here is vmcnt(16) so the  \
           rel prefetch stays in flight) */                                   \
        _Pragma("unroll")                                                     \
        for (int nb = 0; nb < 4; ++nb) {                                      \
            o[nb] = MFMA16(ap0, vf0[nb], o[nb]);                              \
            o[nb] = MFMA16(ap1, vf1[nb], o[nb]);                              \
        }                                                                     \
    }

    for (int kt = 0; kt < 16; kt += 2) {
        TILE_BODY(kt, rbA, rbB)
        TILE_BODY(kt + 1, rbB, rbA)
    }
#undef TILE_BODY

    // ---- epilogue ---------------------------------------------------------
#pragma unroll
    for (int rj = 0; rj < 4; ++rj) {
        const float linv = 1.0f / l_run[rj];
        const int qrow = q0w + quad * 4 + rj;
#pragma unroll
        for (int nb = 0; nb < 4; ++nb)
            out[((size_t)(b * Sc + qrow)) * Hc + h * HDc + nb * 16 + l15] =
                o[nb][rj] * linv;
    }
}

extern "C" void kernel_launch(void* const* d_in, const int* in_sizes, int n_in,
                              void* d_out, int out_size, void* d_ws, size_t ws_size,
                              hipStream_t stream) {
    const float* hs   = (const float*)d_in[0];
    const float* mask = (const float*)d_in[1];
    const float* rel  = (const float*)d_in[2];
    const float* Wq   = (const float*)d_in[3];
    const float* bq   = (const float*)d_in[4];
    const float* Wk   = (const float*)d_in[5];
    const float* bk   = (const float*)d_in[6];
    const float* Wv   = (const float*)d_in[7];
    const float* bv   = (const float*)d_in[8];
    float* out = (float*)d_out;

    const size_t elems = (size_t)Bc * Sc * Hc;        // 4,194,304
    _Float16* hs16 = (_Float16*)d_ws;                 // 8 MB
    _Float16* w16  = hs16 + elems;                    // 1.5 MB
    _Float16* qws  = w16 + (size_t)3 * Hc * Hc;       // 8 MB
    _Float16* kws  = qws + elems;                     // 8 MB
    _Float16* vws  = kws + elems;                     // 8 MB   (total ~33.5 MB)

    const int cvt_blocks = (int)(((size_t)Bc * Sc * Hc + 3 * Hc * Hc) / 4 / 256);
    cvt_f16<<<cvt_blocks, 256, 0, stream>>>(hs, Wq, Wk, Wv, hs16, w16);
    qkv_gemm<<<dim3(64, 12), 256, 0, stream>>>(hs16, w16, bq, bk, bv,
                                               qws, kws, vws);
    attn<<<dim3(32, 64), 128, 0, stream>>>(qws, kws, vws, rel, mask, out);
}

// Round 2
// 490.003 us; speedup vs baseline: 1.0023x; 1.0023x over previous
//
#include <hip/hip_runtime.h>

typedef _Float16 f16x8 __attribute__((ext_vector_type(8)));
typedef _Float16 f16x4 __attribute__((ext_vector_type(4)));
typedef float    f32x4 __attribute__((ext_vector_type(4)));

#define MFMA16(a,b,c) __builtin_amdgcn_mfma_f32_16x16x32_f16((a),(b),(c),0,0,0)

constexpr int Bc  = 8;
constexpr int Sc  = 1024;
constexpr int Hc  = 512;
constexpr int NHc = 8;
constexpr int HDc = 64;

// ---------------------------------------------------------------------------
// Stage 0: fp32 -> fp16 convert of hs and the three W matrices (concatenated).
// ---------------------------------------------------------------------------
__global__ __launch_bounds__(256) void cvt_f16(
    const float* __restrict__ hs,
    const float* __restrict__ wq, const float* __restrict__ wk,
    const float* __restrict__ wv,
    _Float16* __restrict__ hs16, _Float16* __restrict__ w16)
{
    const size_t i4  = (size_t)blockIdx.x * 256 + threadIdx.x;  // float4 index
    const size_t HS4 = (size_t)Bc * Sc * Hc / 4;   // 1,048,576
    const size_t W4  = (size_t)Hc * Hc / 4;        // 65,536
    float4 v;
    _Float16* dst;
    if (i4 < HS4) {
        v = ((const float4*)hs)[i4];
        dst = hs16 + i4 * 4;
    } else {
        const size_t j = i4 - HS4;
        const int z = (int)(j / W4);
        const size_t o = j - (size_t)z * W4;
        const float* src = (z == 0) ? wq : (z == 1) ? wk : wv;
        v = ((const float4*)src)[o];
        dst = w16 + j * 4;
    }
    f16x4 h;
    h[0] = (_Float16)v.x; h[1] = (_Float16)v.y;
    h[2] = (_Float16)v.z; h[3] = (_Float16)v.w;
    *(f16x4*)dst = h;
}

// ---------------------------------------------------------------------------
// Stage 1: fused QKV GEMM, m97-style (unchanged).
// ---------------------------------------------------------------------------
__global__ __launch_bounds__(256) void qkv_gemm(
    const _Float16* __restrict__ A,   // [8192][512]
    const _Float16* __restrict__ Bm,  // [1536][512]
    const float* __restrict__ bq, const float* __restrict__ bk,
    const float* __restrict__ bv,
    _Float16* __restrict__ qws, _Float16* __restrict__ kws,
    _Float16* __restrict__ vws)
{
    __shared__ __align__(16) _Float16 As[128 * 64];
    __shared__ __align__(16) _Float16 Bs[128 * 64];

    const int m0 = blockIdx.x * 128;
    const int n0 = blockIdx.y * 128;
    const int tid  = threadIdx.x;
    const int lane = tid & 63;
    const int w    = tid >> 6;
    const int l15  = lane & 15;
    const int quad = lane >> 4;
    const int wm   = (w >> 1) * 64;
    const int wn   = (w & 1) * 64;

    f32x4 acc[4][4] = {};

    const int srow = tid >> 3;
    const int scol = (tid & 7) * 8;

    for (int k0 = 0; k0 < 512; k0 += 64) {
        __syncthreads();
#pragma unroll
        for (int j = 0; j < 4; ++j) {
            const _Float16* ga = A  + (size_t)(m0 + srow + 32 * j) * 512 + k0 + scol;
            const _Float16* gb = Bm + (size_t)(n0 + srow + 32 * j) * 512 + k0 + scol;
            __builtin_amdgcn_global_load_lds(
                (const __attribute__((address_space(1))) void*)ga,
                (__attribute__((address_space(3))) void*)(As + tid * 8 + j * 2048),
                16, 0, 0);
            __builtin_amdgcn_global_load_lds(
                (const __attribute__((address_space(1))) void*)gb,
                (__attribute__((address_space(3))) void*)(Bs + tid * 8 + j * 2048),
                16, 0, 0);
        }
        __syncthreads();
#pragma unroll
        for (int ks = 0; ks < 2; ++ks) {
            f16x8 af[4], bf[4];
#pragma unroll
            for (int i = 0; i < 4; ++i) {
                af[i] = *(const f16x8*)&As[(wm + i * 16 + l15) * 64 + ks * 32 + quad * 8];
                bf[i] = *(const f16x8*)&Bs[(wn + i * 16 + l15) * 64 + ks * 32 + quad * 8];
            }
#pragma unroll
            for (int mb = 0; mb < 4; ++mb)
#pragma unroll
                for (int nb = 0; nb < 4; ++nb)
                    acc[mb][nb] = MFMA16(af[mb], bf[nb], acc[mb][nb]);
        }
    }

    const int zsel = n0 >> 9;
    const float* bias = (zsel == 0) ? bq : (zsel == 1) ? bk : bv;
#pragma unroll
    for (int nb = 0; nb < 4; ++nb) {
        const int n  = n0 + wn + nb * 16 + l15;
        const int nn = n & 511;
        const int h  = nn >> 6;
        const int hd = nn & 63;
        const float bvv = bias[nn];
#pragma unroll
        for (int mb = 0; mb < 4; ++mb) {
            const int m = m0 + wm + mb * 16 + quad * 4;
            const int b = m >> 10;
            const int s = m & 1023;
            if (zsel == 2) {
                f16x4 t;
#pragma unroll
                for (int rr = 0; rr < 4; ++rr)
                    t[rr] = (_Float16)(acc[mb][nb][rr] + bvv);
                *(f16x4*)&vws[((size_t)(b * NHc + h) * HDc + hd) * Sc + s] = t;
            } else {
                _Float16* dst = (zsel == 0 ? qws : kws)
                              + ((size_t)(b * NHc + h) * Sc + s) * HDc + hd;
#pragma unroll
                for (int rr = 0; rr < 4; ++rr)
                    dst[(size_t)rr * HDc] = (_Float16)(acc[mb][nb][rr] + bvv);
            }
        }
    }
}

// ---------------------------------------------------------------------------
// Stage 2: flash attention. v6: producer/consumer wave split.
//
// v5 post-mortem: in-order vmcnt means ANY wait for the (fast, L2) K loads
// drains the (slow, HBM) rel loads issued before them -> rel flight capped at
// ~1 tile ~250cy << 900cy HBM latency -> 1.4 TB/s, latency-bound.
//
// v6: rel gets its OWN vmcnt queue. Block = 3 waves: waves 0,1 compute
// (v4 math, 16 q-rows each); wave 2 is a pure producer streaming rel tiles
// (32 rows x 64 cols fp32 = 8 KB) into a 4-deep LDS ring via global_load_lds
// (no VGPR cost, counted vmcnt(16) waits -> 2-tile flight >> HBM latency).
// Sync = raw s_barrier (NOT __syncthreads: that would insert vmcnt(0) and
// drain the producer pipeline). Both paths execute exactly 16 barriers.
// Ring safety (B=4): producer writes tile kt+2 in window (bar kt-1, bar kt+2);
// the aliasing read of tile kt-2 is in (bar kt-2, bar kt-1) - disjoint.
// Consumers' global queue now holds only K/V (L2-resident, ~250cy) whose
// waits drain nothing precious; rel arrives via lgkm (ds_read), independent.
// Per CU: 4 blocks x 2 tiles x 8 KB = 64 KB rel in flight >> ~22 KB needed
// to saturate HBM -> attn becomes HBM-streaming-bound (~256 MB -> ~45-60 us).
// ---------------------------------------------------------------------------
__global__ __launch_bounds__(192, 3) void attn(
    const _Float16* __restrict__ qws, const _Float16* __restrict__ kws,
    const _Float16* __restrict__ vws, const float* __restrict__ rel,
    const float* __restrict__ mask, float* __restrict__ out)
{
    const int qt = blockIdx.x;      // 0..31 (32 q-rows per block)
    const int bh = blockIdx.y;      // 0..63
    const int b  = bh >> 3;
    const int h  = bh & 7;
    const int tid  = threadIdx.x;
    const int wv   = tid >> 6;      // 0,1 = consumers; 2 = producer
    const int lane = tid & 63;
    const int l15  = lane & 15;
    const int quad = lane >> 4;

    __shared__ __align__(16) float    rel_buf[4][32 * 64];   // 32 KB ring
    __shared__ __align__(16) _Float16 lds_p[2][16][72];      // per-wave slice

    const _Float16* qh = qws + (size_t)bh * Sc * HDc;
    const _Float16* kh = kws + (size_t)bh * Sc * HDc;
    const _Float16* vh = vws + (size_t)bh * HDc * Sc;
    const float* relh  = rel + (size_t)bh * Sc * Sc;
    const float* maskb = mask + (size_t)b * Sc;
    const int q0 = qt * 32;

    if (wv == 2) {
        // ---------------- producer wave ------------------------------------
        const int prow = lane >> 4;        // 0..3  (row within 4-row chunk)
        const int pcol = (lane & 15) * 4;  // float col (16B per lane)

#define ISSUE_TILE(T)                                                         \
        {                                                                     \
            _Pragma("unroll")                                                 \
            for (int g = 0; g < 8; ++g) {                                     \
                const int R = g * 4 + prow;                                   \
                const float* src = relh + (size_t)(q0 + R) * Sc               \
                                 + (T) * 64 + pcol;                           \
                float* dst = &rel_buf[(T) & 3][g * 256 + lane * 4];           \
                __builtin_amdgcn_global_load_lds(                             \
                    (const __attribute__((address_space(1))) void*)src,       \
                    (__attribute__((address_space(3))) void*)dst, 16, 0, 0);  \
            }                                                                 \
        }

        ISSUE_TILE(0)
        ISSUE_TILE(1)
        for (int kt = 0; kt < 16; ++kt) {
            if (kt + 2 < 16) ISSUE_TILE(kt + 2)
            if (kt <= 13) {
                asm volatile("s_waitcnt vmcnt(16)" ::: "memory");
            } else if (kt == 14) {
                asm volatile("s_waitcnt vmcnt(8)" ::: "memory");
            } else {
                asm volatile("s_waitcnt vmcnt(0)" ::: "memory");
            }
            __builtin_amdgcn_sched_barrier(0);
            __builtin_amdgcn_s_barrier();
            __builtin_amdgcn_sched_barrier(0);
        }
#undef ISSUE_TILE
        return;
    }

    // -------------------- consumer waves (0,1) -----------------------------
    const int w   = wv;
    const int q0w = q0 + w * 16;

    f16x8 qf0 = *(const f16x8*)(qh + (size_t)(q0w + l15) * HDc + quad * 8);
    f16x8 qf1 = *(const f16x8*)(qh + (size_t)(q0w + l15) * HDc + 32 + quad * 8);

    float m_run[4], l_run[4];
    f32x4 o[4] = {};
#pragma unroll
    for (int rj = 0; rj < 4; ++rj) { m_run[rj] = -1e30f; l_run[rj] = 0.f; }

    for (int kt = 0; kt < 16; ++kt) {
        __builtin_amdgcn_sched_barrier(0);
        __builtin_amdgcn_s_barrier();          // buf kt ready
        __builtin_amdgcn_sched_barrier(0);

        const int kbase = kt * 64;
        const float* rbuf = rel_buf[kt & 3];

        // rel bias from LDS (lgkm queue - independent of K/V vmcnt waits)
        float rb[16];
#pragma unroll
        for (int nb = 0; nb < 4; ++nb)
#pragma unroll
            for (int rj = 0; rj < 4; ++rj)
                rb[nb * 4 + rj] =
                    rbuf[(w * 16 + quad * 4 + rj) * 64 + nb * 16 + l15];

        float mk[4];
#pragma unroll
        for (int nb = 0; nb < 4; ++nb)
            mk[nb] = maskb[kbase + nb * 16 + l15];

        f16x8 kf0[4], kf1[4];
#pragma unroll
        for (int nb = 0; nb < 4; ++nb) {
            const _Float16* kp = kh + (size_t)(kbase + nb * 16 + l15) * HDc + quad * 8;
            kf0[nb] = *(const f16x8*)kp;
            kf1[nb] = *(const f16x8*)(kp + 32);
        }
        f16x8 vf0[4], vf1[4];
#pragma unroll
        for (int nb = 0; nb < 4; ++nb) {
            const _Float16* vp = vh + (size_t)(nb * 16 + l15) * Sc + kbase + quad * 8;
            vf0[nb] = *(const f16x8*)vp;
            vf1[nb] = *(const f16x8*)(vp + 32);
        }

        // ---- S = Q K^T ----------------------------------------------------
        f32x4 sc[4] = {};
#pragma unroll
        for (int nb = 0; nb < 4; ++nb) {
            sc[nb] = MFMA16(qf0, kf0[nb], sc[nb]);
            sc[nb] = MFMA16(qf1, kf1[nb], sc[nb]);
        }

        // ---- scale + rel bias + mask (C layout: col=l15, row=quad*4+rj) ---
#pragma unroll
        for (int nb = 0; nb < 4; ++nb)
#pragma unroll
            for (int rj = 0; rj < 4; ++rj)
                sc[nb][rj] = sc[nb][rj] * 0.125f + rb[nb * 4 + rj] + mk[nb];

        // ---- online softmax (row lives on 16 lanes of one quad) -----------
#pragma unroll
        for (int rj = 0; rj < 4; ++rj) {
            float mx = fmaxf(fmaxf(sc[0][rj], sc[1][rj]), fmaxf(sc[2][rj], sc[3][rj]));
#pragma unroll
            for (int off = 1; off < 16; off <<= 1) mx = fmaxf(mx, __shfl_xor(mx, off));
            const float mnew  = fmaxf(m_run[rj], mx);
            const float alpha = __expf(m_run[rj] - mnew);
            float rs = 0.f;
#pragma unroll
            for (int nb = 0; nb < 4; ++nb) {
                const float p = __expf(sc[nb][rj] - mnew);
                sc[nb][rj] = p;
                rs += p;
            }
#pragma unroll
            for (int off = 1; off < 16; off <<= 1) rs += __shfl_xor(rs, off);
            m_run[rj] = mnew;
            l_run[rj] = l_run[rj] * alpha + rs;
            o[0][rj] *= alpha; o[1][rj] *= alpha; o[2][rj] *= alpha; o[3][rj] *= alpha;
        }

        // ---- P: C layout -> A layout via per-wave LDS (no barriers) -------
#pragma unroll
        for (int nb = 0; nb < 4; ++nb)
#pragma unroll
            for (int rj = 0; rj < 4; ++rj)
                lds_p[w][quad * 4 + rj][nb * 16 + l15] = (_Float16)sc[nb][rj];
        f16x8 ap0 = *(const f16x8*)&lds_p[w][l15][quad * 8];
        f16x8 ap1 = *(const f16x8*)&lds_p[w][l15][32 + quad * 8];

        // ---- O += P V  (B operand from V^T; V preloaded at tile top) ------
#pragma unroll
        for (int nb = 0; nb < 4; ++nb) {
            o[nb] = MFMA16(ap0, vf0[nb], o[nb]);
            o[nb] = MFMA16(ap1, vf1[nb], o[nb]);
        }
    }

    // ---- epilogue ---------------------------------------------------------
#pragma unroll
    for (int rj = 0; rj < 4; ++rj) {
        const float linv = 1.0f / l_run[rj];
        const int qrow = q0w + quad * 4 + rj;
#pragma unroll
        for (int nb = 0; nb < 4; ++nb)
            out[((size_t)(b * Sc + qrow)) * Hc + h * HDc + nb * 16 + l15] =
                o[nb][rj] * linv;
    }
}

extern "C" void kernel_launch(void* const* d_in, const int* in_sizes, int n_in,
                              void* d_out, int out_size, void* d_ws, size_t ws_size,
                              hipStream_t stream) {
    const float* hs   = (const float*)d_in[0];
    const float* mask = (const float*)d_in[1];
    const float* rel  = (const float*)d_in[2];
    const float* Wq   = (const float*)d_in[3];
    const float* bq   = (const float*)d_in[4];
    const float* Wk   = (const float*)d_in[5];
    const float* bk   = (const float*)d_in[6];
    const float* Wv   = (const float*)d_in[7];
    const float* bv   = (const float*)d_in[8];
    float* out = (float*)d_out;

    const size_t elems = (size_t)Bc * Sc * Hc;        // 4,194,304
    _Float16* hs16 = (_Float16*)d_ws;                 // 8 MB
    _Float16* w16  = hs16 + elems;                    // 1.5 MB
    _Float16* qws  = w16 + (size_t)3 * Hc * Hc;       // 8 MB
    _Float16* kws  = qws + elems;                     // 8 MB
    _Float16* vws  = kws + elems;                     // 8 MB   (total ~33.5 MB)

    const int cvt_blocks = (int)(((size_t)Bc * Sc * Hc + 3 * Hc * Hc) / 4 / 256);
    cvt_f16<<<cvt_blocks, 256, 0, stream>>>(hs, Wq, Wk, Wv, hs16, w16);
    qkv_gemm<<<dim3(64, 12), 256, 0, stream>>>(hs16, w16, bq, bk, bv,
                                               qws, kws, vws);
    attn<<<dim3(32, 64), 192, 0, stream>>>(qws, kws, vws, rel, mask, out);
}